// Round 5
// baseline (225.286 us; speedup 1.0000x reference)
//
#include <hip/hip_runtime.h>
#include <hip/hip_bf16.h>

#define DIN 4096
#define DOUT 4096
#define NROWS 8192  // B*S = 4*2048

typedef int i32x4 __attribute__((ext_vector_type(4)));

// ---------------- block-level absmax reduce (4 waves, 256 threads) -------------
__device__ __forceinline__ float block_absmax(float m, float* red) {
  #pragma unroll
  for (int off = 32; off > 0; off >>= 1)
    m = fmaxf(m, __shfl_down(m, off));
  const int tid = threadIdx.x;
  if ((tid & 63) == 0) red[tid >> 6] = m;
  __syncthreads();
  return fmaxf(fmaxf(red[0], red[1]), fmaxf(red[2], red[3]));
}

// ---------------- kernel 1: FWHT (radix-16, bit-exact order) + 8b quant --------
__global__ __launch_bounds__(256) void fwht_quant_kernel(
    const float* __restrict__ in, char* __restrict__ qx,
    float* __restrict__ sx) {
  __shared__ float lds[4352];  // 4096 + 256 pad
  __shared__ float red[4];
  const int tid = threadIdx.x;
  const size_t row = blockIdx.x;
  const int th = tid >> 4, tl = tid & 15;
  float v[16];

  const float4* src = (const float4*)(in + row * DIN);
  #pragma unroll
  for (int k = 0; k < 4; ++k) {
    float4 f = src[tid * 4 + k];
    v[4 * k + 0] = f.x; v[4 * k + 1] = f.y;
    v[4 * k + 2] = f.z; v[4 * k + 3] = f.w;
  }
  #pragma unroll
  for (int hb = 1; hb < 16; hb <<= 1)
    #pragma unroll
    for (int j = 0; j < 16; ++j)
      if (!(j & hb)) {
        float a0 = v[j], b0 = v[j | hb];
        v[j] = a0 + b0; v[j | hb] = a0 - b0;
      }
  #pragma unroll
  for (int j = 0; j < 16; ++j) lds[17 * tid + j] = v[j];
  __syncthreads();
  #pragma unroll
  for (int j = 0; j < 16; ++j) v[j] = lds[272 * th + 17 * j + tl];
  #pragma unroll
  for (int hb = 1; hb < 16; hb <<= 1)
    #pragma unroll
    for (int j = 0; j < 16; ++j)
      if (!(j & hb)) {
        float a0 = v[j], b0 = v[j | hb];
        v[j] = a0 + b0; v[j | hb] = a0 - b0;
      }
  #pragma unroll
  for (int j = 0; j < 16; ++j) lds[272 * th + 17 * j + tl] = v[j];
  __syncthreads();
  #pragma unroll
  for (int j = 0; j < 16; ++j) v[j] = lds[272 * j + 17 * th + tl];
  #pragma unroll
  for (int hb = 1; hb < 16; hb <<= 1)
    #pragma unroll
    for (int j = 0; j < 16; ++j)
      if (!(j & hb)) {
        float a0 = v[j], b0 = v[j | hb];
        v[j] = a0 + b0; v[j | hb] = a0 - b0;
      }
  float m = 0.0f;
  #pragma unroll
  for (int j = 0; j < 16; ++j) m = fmaxf(m, fabsf(v[j]));
  #pragma unroll
  for (int j = 0; j < 16; ++j) lds[272 * j + 17 * th + tl] = v[j];
  float mx = block_absmax(m, red) * 0.015625f;
  float scale = fmaxf(mx / 127.0f, 1e-8f);
  if (tid == 0) sx[row] = scale;
  const float rs = 1.0f / scale;
  char pk[16];
  #pragma unroll
  for (int j = 0; j < 16; ++j) {
    float q = fminf(fmaxf(rintf((lds[17 * tid + j] * 0.015625f) * rs), -127.f),
                    127.f);
    pk[j] = (char)q;
  }
  *(int4*)(qx + row * DIN + (size_t)tid * 16) = *(const int4*)pk;
}

// ---------------- kernel 2: per-channel 4-bit weight quant -> int8 -------------
__global__ __launch_bounds__(256) void wquant_kernel(
    const float* __restrict__ w, char* __restrict__ qw,
    float* __restrict__ sw) {
  __shared__ float buf[DIN];
  __shared__ float red[4];
  const int tid = threadIdx.x;
  const size_t row = blockIdx.x;
  const float4* src = (const float4*)(w + row * DIN);
  float4* b4 = (float4*)buf;
  float m = 0.0f;
  for (int i = tid; i < DIN / 4; i += 256) {
    float4 v = src[i];
    b4[i] = v;
    m = fmaxf(m, fmaxf(fmaxf(fabsf(v.x), fabsf(v.y)),
                       fmaxf(fabsf(v.z), fabsf(v.w))));
  }
  float mx = block_absmax(m, red);
  float scale = fmaxf(mx / 7.0f, 1e-8f);
  if (tid == 0) sw[row] = scale;
  char* dst = qw + row * DIN;
  const float rs = 1.0f / scale;
  for (int i0 = tid * 4; i0 < DIN; i0 += 1024) {
    char4 pk;
    float q0 = fminf(fmaxf(rintf(buf[i0 + 0] * rs), -7.f), 7.f);
    float q1 = fminf(fmaxf(rintf(buf[i0 + 1] * rs), -7.f), 7.f);
    float q2 = fminf(fmaxf(rintf(buf[i0 + 2] * rs), -7.f), 7.f);
    float q3 = fminf(fmaxf(rintf(buf[i0 + 3] * rs), -7.f), 7.f);
    pk.x = (char)q0; pk.y = (char)q1; pk.z = (char)q2; pk.w = (char)q3;
    *(char4*)(dst + i0) = pk;
  }
}

// ---------------- kernel 3: i8 MFMA GEMM, 256x256 tile, 8-phase schedule -------
// R2-proven skeleton. MFMA operands SWAPPED (mfma(fb,fa)) so acc holds C^T
// fragments: lane&15 -> output row, 4*(lane>>4)+reg -> output col => float4
// C-stores. Swizzle: 16B-slot ^= (row&7) on pre-swizzled global src + ds_read.
__global__ __launch_bounds__(512, 2) void gemm_kernel(
    const char* __restrict__ A,   // [NROWS][DIN] q_x int8
    const char* __restrict__ Bt,  // [DOUT][DIN]  q_w int8
    const float* __restrict__ sx, const float* __restrict__ sw,
    const float* __restrict__ bias, float* __restrict__ out) {
  __shared__ char lds[131072];
  const int tid = threadIdx.x;
  const int lane = tid & 63;
  const int wid = tid >> 6;
  const int wr = wid >> 2;  // 0..1
  const int wc = wid & 3;   // 0..3
  int bid = blockIdx.x;                    // 512 blocks
  int swz = (bid & 7) * 64 + (bid >> 3);   // bijective XCD swizzle (512%8==0)
  const int tm = swz >> 4;                 // 0..31
  const int tn = swz & 15;                 // 0..15
  const size_t row0 = (size_t)tm * 256;
  const size_t col0 = (size_t)tn * 256;
  const int slot0 = (((lane >> 4) ^ (lane & 7)) << 4);  // swizzled 16B slot

  i32x4 acc[4][2][4] = {};  // [slab q][mm][nn] — C^T fragments
  i32x4 fb[4][2];           // [nn][kk] — persists across a 4-phase group
  i32x4 fa[2][2];           // [mm][kk] — per phase

#define STAGE(MAT, GROW0, KT, LBASE)                                          \
  {                                                                           \
    _Pragma("unroll")                                                         \
    for (int j = 0; j < 2; ++j) {                                             \
      int chunk = j * 8 + wid;                                                \
      int rr = chunk * 8 + (lane >> 3);                                       \
      int cc = (KT) * 128 + (((lane & 7) ^ (lane >> 3)) << 4);                \
      const char* src = (MAT) + ((GROW0) + rr) * (size_t)DIN + cc;            \
      __builtin_amdgcn_global_load_lds(                                       \
          (const __attribute__((address_space(1))) void*)src,                 \
          (__attribute__((address_space(3))) void*)(lds + (LBASE) +           \
                                                    chunk * 1024),            \
          16, 0, 0);                                                          \
    }                                                                         \
  }
#define STAGE_A(P, HALF, KT) \
  STAGE(A, row0 + (HALF) * 128, KT, (P) * 32768 + (HALF) * 16384)
#define STAGE_B(P, HALF, KT) \
  STAGE(Bt, col0 + (HALF) * 128, KT, 65536 + (P) * 32768 + (HALF) * 16384)

#define DS_A(Q, P)                                                            \
  {                                                                           \
    _Pragma("unroll")                                                         \
    for (int mm = 0; mm < 2; ++mm) {                                          \
      int ar = (Q) * 64 + wr * 32 + mm * 16 + (lane & 15);                    \
      _Pragma("unroll")                                                       \
      for (int kk = 0; kk < 2; ++kk)                                          \
        fa[mm][kk] =                                                          \
            *(const i32x4*)(lds + (P) * 32768 + ar * 128 + (slot0 ^ (kk * 64))); \
    }                                                                         \
  }
#define DS_B(P)                                                               \
  {                                                                           \
    _Pragma("unroll")                                                         \
    for (int nn = 0; nn < 4; ++nn) {                                          \
      int br = wc * 64 + nn * 16 + (lane & 15);                               \
      _Pragma("unroll")                                                       \
      for (int kk = 0; kk < 2; ++kk)                                          \
        fb[nn][kk] = *(const i32x4*)(lds + 65536 + (P) * 32768 + br * 128 +   \
                                     (slot0 ^ (kk * 64)));                    \
    }                                                                         \
  }
#define MFMA16(Q)                                                             \
  {                                                                           \
    __builtin_amdgcn_s_setprio(1);                                            \
    _Pragma("unroll")                                                         \
    for (int kk = 0; kk < 2; ++kk)                                            \
      _Pragma("unroll")                                                       \
      for (int mm = 0; mm < 2; ++mm)                                          \
        _Pragma("unroll")                                                     \
        for (int nn = 0; nn < 4; ++nn)                                        \
          acc[Q][mm][nn] = __builtin_amdgcn_mfma_i32_16x16x64_i8(             \
              fb[nn][kk], fa[mm][kk], acc[Q][mm][nn], 0, 0, 0);               \
    __builtin_amdgcn_s_setprio(0);                                            \
  }
#define BAR() __builtin_amdgcn_s_barrier()
#define WAIT_LGKM0() asm volatile("s_waitcnt lgkmcnt(0)" ::: "memory")

  // -------- prologue: kt0 -> buf0 (4 half-tiles), kt1 -> buf1 (3 half-tiles)
  STAGE_B(0, 0, 0); STAGE_B(0, 1, 0); STAGE_A(0, 0, 0); STAGE_A(0, 1, 0);
  STAGE_B(1, 0, 1); STAGE_B(1, 1, 1); STAGE_A(1, 0, 1);
  asm volatile("s_waitcnt vmcnt(6)" ::: "memory");  // buf0 fully landed
  BAR();

  #pragma unroll 1
  for (int i = 0; i < 16; ++i) {
    const int a = 2 * i, b = 2 * i + 1;
    const bool nl = (i < 15);
    // ---- ph1: slab0 of buf0; stage buf1.A-h1 <- kt b (completes buf1)
    DS_A(0, 0); DS_B(0);
    STAGE_A(1, 1, b);
    asm volatile("s_waitcnt lgkmcnt(8)" ::: "memory");
    BAR(); WAIT_LGKM0();
    MFMA16(0);
    BAR();
    // ---- ph2: slab1 of buf0; stage buf0.B-h0 <- kt a+2
    DS_A(1, 0);
    if (nl) STAGE_B(0, 0, a + 2);
    BAR(); WAIT_LGKM0();
    MFMA16(1);
    BAR();
    // ---- ph3: slab2; stage buf0.B-h1
    DS_A(2, 0);
    if (nl) STAGE_B(0, 1, a + 2);
    BAR(); WAIT_LGKM0();
    MFMA16(2);
    BAR();
    // ---- ph4: slab3; stage buf0.A-h0; vmcnt -> buf1 ready
    DS_A(3, 0);
    if (nl) STAGE_A(0, 0, a + 2);
    BAR(); WAIT_LGKM0();
    MFMA16(3);
    if (nl) { asm volatile("s_waitcnt vmcnt(6)" ::: "memory"); }
    else    { asm volatile("s_waitcnt vmcnt(0)" ::: "memory"); }
    BAR();
    // ---- ph5: slab0 of buf1; stage buf0.A-h1
    DS_A(0, 1); DS_B(1);
    if (nl) STAGE_A(0, 1, a + 2);
    asm volatile("s_waitcnt lgkmcnt(8)" ::: "memory");
    BAR(); WAIT_LGKM0();
    MFMA16(0);
    BAR();
    // ---- ph6: slab1 of buf1; stage buf1.B-h0 <- kt b+2
    DS_A(1, 1);
    if (nl) STAGE_B(1, 0, b + 2);
    BAR(); WAIT_LGKM0();
    MFMA16(1);
    BAR();
    // ---- ph7: slab2; stage buf1.B-h1
    DS_A(2, 1);
    if (nl) STAGE_B(1, 1, b + 2);
    BAR(); WAIT_LGKM0();
    MFMA16(2);
    BAR();
    // ---- ph8: slab3; stage buf1.A-h0; vmcnt -> buf0 ready for next iter
    DS_A(3, 1);
    if (nl) STAGE_A(1, 0, b + 2);
    BAR(); WAIT_LGKM0();
    MFMA16(3);
    if (nl) { asm volatile("s_waitcnt vmcnt(6)" ::: "memory"); }
    BAR();
  }

  // -------- epilogue (C^T frags): lane row gr = base+(lane&15);
  // 4 consecutive cols per reg group => float4 stores.
  #pragma unroll
  for (int q = 0; q < 4; ++q) {
    #pragma unroll
    for (int mm = 0; mm < 2; ++mm) {
      size_t gr = row0 + q * 64 + wr * 32 + mm * 16 + (lane & 15);
      float sxr = sx[gr];
      float* orow = out + gr * DOUT;
      #pragma unroll
      for (int nn = 0; nn < 4; ++nn) {
        size_t gc0 = col0 + wc * 64 + nn * 16 + ((lane >> 4) << 2);
        float4 swv = *(const float4*)(sw + gc0);
        float4 bv = *(const float4*)(bias + gc0);
        float4 o;
        o.x = (float)acc[q][mm][nn][0] * (sxr * swv.x) + bv.x;
        o.y = (float)acc[q][mm][nn][1] * (sxr * swv.y) + bv.y;
        o.z = (float)acc[q][mm][nn][2] * (sxr * swv.z) + bv.z;
        o.w = (float)acc[q][mm][nn][3] * (sxr * swv.w) + bv.w;
        *(float4*)(orow + gc0) = o;
      }
    }
  }
#undef STAGE
#undef STAGE_A
#undef STAGE_B
#undef DS_A
#undef DS_B
#undef MFMA16
#undef BAR
#undef WAIT_LGKM0
}

// ---------------- kernel 4: per-token 8-bit fake quant of output, in place ----
__global__ __launch_bounds__(256) void rowquant_kernel(float* __restrict__ out) {
  __shared__ float red[4];
  const int tid = threadIdx.x;
  const size_t row = blockIdx.x;
  float4* g4 = (float4*)(out + row * DOUT);
  float4 v[4];
  float m = 0.0f;
  #pragma unroll
  for (int k = 0; k < 4; ++k) {
    v[k] = g4[tid + k * 256];
    m = fmaxf(m, fmaxf(fmaxf(fabsf(v[k].x), fabsf(v[k].y)),
                       fmaxf(fabsf(v[k].z), fabsf(v[k].w))));
  }
  float mx = block_absmax(m, red);
  float scale = fmaxf(mx / 127.0f, 1e-8f);
  #pragma unroll
  for (int k = 0; k < 4; ++k) {
    float4 w = v[k];
    w.x = fminf(fmaxf(rintf(w.x / scale), -127.0f), 127.0f) * scale;
    w.y = fminf(fmaxf(rintf(w.y / scale), -127.0f), 127.0f) * scale;
    w.z = fminf(fmaxf(rintf(w.z / scale), -127.0f), 127.0f) * scale;
    w.w = fminf(fmaxf(rintf(w.w / scale), -127.0f), 127.0f) * scale;
    g4[tid + k * 256] = w;
  }
}

extern "C" void kernel_launch(void* const* d_in, const int* in_sizes, int n_in,
                              void* d_out, int out_size, void* d_ws, size_t ws_size,
                              hipStream_t stream) {
  (void)in_sizes; (void)n_in; (void)out_size; (void)ws_size;
  const float* input = (const float*)d_in[0];
  const float* weight = (const float*)d_in[1];
  const float* bias = (const float*)d_in[2];
  float* out = (float*)d_out;
  char* ws = (char*)d_ws;
  char* qx = ws;
  char* qw = ws + ((size_t)32 << 20);
  float* sx = (float*)(ws + ((size_t)48 << 20));
  float* sw = (float*)(ws + ((size_t)48 << 20) + ((size_t)32 << 10));

  fwht_quant_kernel<<<NROWS, 256, 0, stream>>>(input, qx, sx);
  wquant_kernel<<<DOUT, 256, 0, stream>>>(weight, qw, sw);
  gemm_kernel<<<512, 512, 0, stream>>>(qx, qw, sx, sw, bias, out);
  rowquant_kernel<<<NROWS, 256, 0, stream>>>(out);
}